// Round 15
// baseline (441.554 us; speedup 1.0000x reference)
//
#include <hip/hip_runtime.h>
#include <hip/hip_bf16.h>
#include <math.h>

#define Bb 2
#define Ss 4096
#define Dd 512
#define Hh 8
#define Ff 2048
#define Mm 8192   // Bb*Ss
#define QT3 1536  // 3*Dd, merged qkv row stride
#define KVB 128   // kv tile
#define CSTEPS 8  // steps per kv-chunk (8*128 = 1024 keys)

typedef float  f32x4  __attribute__((ext_vector_type(4)));
typedef short  bf16x8 __attribute__((ext_vector_type(8)));

__device__ __forceinline__ ushort f2bf(float f) {
  union { float f; uint u; } c; c.f = f;
  uint u = c.u;
  uint r = (u + 0x7fffu + ((u >> 16) & 1u)) >> 16;  // RNE
  return (ushort)r;
}
__device__ __forceinline__ float bf2f(ushort u) {
  union { uint u; float f; } c; c.u = (uint)u << 16; return c.f;
}
// cheap round-half-up bf16 (for softmax P >= 0 — bias negligible)
__device__ __forceinline__ ushort f2bf_rhu(float f) {
  union { float f; uint u; } c; c.f = f;
  return (ushort)((c.u + 0x8000u) >> 16);
}

// async global->LDS, 16B per lane; LDS dest is wave-uniform base + lane*16
__device__ __forceinline__ void gload_lds16(const ushort* g, ushort* l) {
  __builtin_amdgcn_global_load_lds(
      (const __attribute__((address_space(1))) void*)g,
      (__attribute__((address_space(3))) void*)l, 16, 0, 0);
}

// ---------------------------------------------------------------------------
// bf16 MFMA GEMM (m97 structure): C[M,N] = A[M,K] @ Bt[N,K]^T + bias.
// BM x 128 tile, BK=32, 256 thr = 4 waves. BM=128: 2x2 waves of 64x64.
// BM=64: 2x2 waves of 32x64 (grid doubles -> 2 blocks/CU for small-N GEMMs).
// ---------------------------------------------------------------------------
template<int BM, bool OUTBF, bool RELU>
__global__ __launch_bounds__(256) void gemm_mfma(const ushort* __restrict__ A,
                                                 const ushort* __restrict__ Bt,
                                                 const float* __restrict__ bias,
                                                 void* __restrict__ Cout,
                                                 int M, int N, int K) {
  constexpr int MI = BM / 32;               // M-frags per wave (4 or 2)
  __shared__ __align__(16) ushort As[BM * 32];
  __shared__ __align__(16) ushort Bs[128 * 32];
  const int t = threadIdx.x;
  const int w = t >> 6, lane = t & 63;
  const int lrow = lane & 15, lhi = lane >> 4;
  const int bm = blockIdx.y * BM, bn = blockIdx.x * 128;
  const int wm = (w >> 1) * (BM / 2), wn = (w & 1) * 64;
  const int sr = t >> 2, sc = (t & 3) * 8;  // staging: row, 8-elem col group

  f32x4 acc[MI][4];
#pragma unroll
  for (int i = 0; i < MI; ++i)
#pragma unroll
    for (int j = 0; j < 4; ++j) acc[i][j] = (f32x4)(0.f);

  const ushort* Ap = A  + (size_t)(bm + sr) * K + sc;
  const ushort* Bp = Bt + (size_t)(bn + sr) * K + sc;
  const size_t rowK64 = (size_t)64 * K;
  ushort* AsW0 = As + w * 512;              // wave-uniform LDS bases
  ushort* AsW1 = As + 2048 + w * 512;       // used only when BM=128
  ushort* BsW0 = Bs + w * 512;
  ushort* BsW1 = Bs + 2048 + w * 512;

  for (int k0 = 0; k0 < K; k0 += 32) {
    __syncthreads();
    gload_lds16(Ap + k0, AsW0);
    if (BM == 128) gload_lds16(Ap + rowK64 + k0, AsW1);
    gload_lds16(Bp + k0,          BsW0);
    gload_lds16(Bp + rowK64 + k0, BsW1);
    __syncthreads();
    bf16x8 af[MI], bfr[4];
#pragma unroll
    for (int i = 0; i < MI; ++i)
      af[i] = *(const bf16x8*)&As[(wm + i * 16 + lrow) * 32 + lhi * 8];
#pragma unroll
    for (int j = 0; j < 4; ++j)
      bfr[j] = *(const bf16x8*)&Bs[(wn + j * 16 + lrow) * 32 + lhi * 8];
#pragma unroll
    for (int i = 0; i < MI; ++i)
#pragma unroll
      for (int j = 0; j < 4; ++j)
        acc[i][j] = __builtin_amdgcn_mfma_f32_16x16x32_bf16(af[i], bfr[j], acc[i][j], 0, 0, 0);
  }

  float bvs[4];
#pragma unroll
  for (int j = 0; j < 4; ++j) bvs[j] = bias[bn + wn + j * 16 + lrow];

#pragma unroll
  for (int i = 0; i < MI; ++i)
#pragma unroll
    for (int r = 0; r < 4; ++r) {
      const int row = bm + wm + i * 16 + lhi * 4 + r;
#pragma unroll
      for (int j = 0; j < 4; ++j) {
        float val = acc[i][j][r] + bvs[j];
        if (RELU) val = fmaxf(val, 0.f);
        const size_t idx = (size_t)row * N + bn + wn + j * 16 + lrow;
        if (OUTBF) ((ushort*)Cout)[idx] = f2bf(val);
        else       ((float*)Cout)[idx]  = val;
      }
    }
}

// ---------------------------------------------------------------------------
// Causal flash attention v4: split-KV. Block = (qt, bh, chunk c of 1024 keys).
// QTILE=64 (4 waves x 16 rows), KVB=128, <=8 steps/block. Writes UNNORMALIZED
// partials: P_O bf16 [bh][qt][c][64row][64dim], P_m/P_l fp32 [bh][qt][c][64].
// exp2-domain softmax + defer-max (exact), per-lane deferred l-reduction.
// ---------------------------------------------------------------------------
__global__ __launch_bounds__(256, 3) void flash_attn_split(const ushort* __restrict__ qkv,
                                                           ushort* __restrict__ P_O,
                                                           float* __restrict__ P_m,
                                                           float* __restrict__ P_l) {
  __shared__ __align__(16) ushort Ks[128][72];   // [key][dim]
  __shared__ __align__(16) ushort Vt[64][136];   // [dim][key]
  __shared__ __align__(16) ushort Ps[4][16][136];

  const int t = threadIdx.x;
  const int w = t >> 6, lane = t & 63;
  const int lrow = lane & 15, lhi = lane >> 4;
  const int qt = 63 - (int)blockIdx.x;           // heavy first
  const int bh = (int)blockIdx.y >> 2, cc = (int)blockIdx.y & 3;
  const int nt_total = (qt + 2) >> 1;
  const int s0 = cc * CSTEPS;
  if (s0 >= nt_total) return;                    // inactive chunk
  const int s_end = min(nt_total, s0 + CSTEPS);

  const int bb = bh >> 3, hh = bh & 7;
  const int q0 = qt * 64;
  const size_t baseq = (size_t)bb * Ss * QT3 + hh * 64;
  const ushort* qp = qkv + baseq;
  const ushort* kp = qkv + baseq + 512;
  const ushort* vp = qkv + baseq + 1024;

  const int krow = t >> 1, kd0 = (t & 1) * 32;   // K stager: 1 key, 32 dims
  const int vk0 = lane * 2, vd0 = w * 16;        // V stager: 2 keys, 16 dims

  // Q fragments: row q0 + w*16 + lrow
  bf16x8 qa[2];
  {
    const ushort* qsrc = qp + (size_t)(q0 + w * 16 + lrow) * QT3;
    qa[0] = *(const bf16x8*)(qsrc + lhi * 8);
    qa[1] = *(const bf16x8*)(qsrc + 32 + lhi * 8);
  }

  float m2[4], lsum[4];
  f32x4 oacc[4];
#pragma unroll
  for (int r = 0; r < 4; ++r) { m2[r] = -INFINITY; lsum[r] = 0.f; }
#pragma unroll
  for (int g = 0; g < 4; ++g) oacc[g] = (f32x4)(0.f);

  const float C2 = 0.18033688f;                  // 0.125 * log2(e)

  // register prefetch of first tile
  bf16x8 kr[4], va[2], vb[2];
  {
    const ushort* ksrc = kp + (size_t)(s0 * KVB + krow) * QT3 + kd0;
#pragma unroll
    for (int j = 0; j < 4; ++j) kr[j] = *(const bf16x8*)(ksrc + j * 8);
    const ushort* vsrc = vp + (size_t)(s0 * KVB + vk0) * QT3 + vd0;
    va[0] = *(const bf16x8*)(vsrc);
    va[1] = *(const bf16x8*)(vsrc + 8);
    vb[0] = *(const bf16x8*)(vsrc + QT3);
    vb[1] = *(const bf16x8*)(vsrc + QT3 + 8);
  }

  for (int s = s0; s < s_end; ++s) {
    const int j0 = s * KVB;

    // ---- staged regs -> LDS ----
    __syncthreads();
#pragma unroll
    for (int j = 0; j < 4; ++j)
      *(bf16x8*)&Ks[krow][kd0 + j * 8] = kr[j];
#pragma unroll
    for (int i = 0; i < 8; ++i) {
      uint p0 = (uint)(ushort)va[0][i] | ((uint)(ushort)vb[0][i] << 16);
      uint p1 = (uint)(ushort)va[1][i] | ((uint)(ushort)vb[1][i] << 16);
      *(uint*)&Vt[vd0 + i][vk0]     = p0;
      *(uint*)&Vt[vd0 + 8 + i][vk0] = p1;
    }
    __syncthreads();

    // ---- issue next tile's loads ----
    if (s + 1 < s_end) {
      const int jn = j0 + KVB;
      const ushort* ksrc = kp + (size_t)(jn + krow) * QT3 + kd0;
#pragma unroll
      for (int j = 0; j < 4; ++j) kr[j] = *(const bf16x8*)(ksrc + j * 8);
      const ushort* vsrc = vp + (size_t)(jn + vk0) * QT3 + vd0;
      va[0] = *(const bf16x8*)(vsrc);
      va[1] = *(const bf16x8*)(vsrc + 8);
      vb[0] = *(const bf16x8*)(vsrc + QT3);
      vb[1] = *(const bf16x8*)(vsrc + QT3 + 8);
    }

    // ---- S = Q K^T ----
    f32x4 sacc[8];
#pragma unroll
    for (int g = 0; g < 8; ++g) sacc[g] = (f32x4)(0.f);
#pragma unroll
    for (int g = 0; g < 8; ++g)
#pragma unroll
      for (int kk = 0; kk < 2; ++kk) {
        bf16x8 kb = *(const bf16x8*)&Ks[g * 16 + lrow][kk * 32 + lhi * 8];
        sacc[g] = __builtin_amdgcn_mfma_f32_16x16x32_bf16(qa[kk], kb, sacc[g], 0, 0, 0);
      }

    // ---- causal mask (diagonal-overlapping tiles only) ----
    if (j0 + KVB - 1 > q0) {
#pragma unroll
      for (int g = 0; g < 8; ++g) {
        const int kcol = j0 + g * 16 + lrow;
#pragma unroll
        for (int r = 0; r < 4; ++r) {
          const int qrow = q0 + w * 16 + lhi * 4 + r;
          if (kcol > qrow) sacc[g][r] = -1e30f;
        }
      }
    }

    // ---- defer-max check ----
    float pm[4];
#pragma unroll
    for (int r = 0; r < 4; ++r) {
      float m01 = fmaxf(sacc[0][r], sacc[1][r]);
      float m23 = fmaxf(sacc[2][r], sacc[3][r]);
      float m45 = fmaxf(sacc[4][r], sacc[5][r]);
      float m67 = fmaxf(sacc[6][r], sacc[7][r]);
      pm[r] = fmaxf(fmaxf(m01, m23), fmaxf(m45, m67));
    }
    bool ok = true;
#pragma unroll
    for (int r = 0; r < 4; ++r) ok = ok && (pm[r] * C2 <= m2[r] + 8.f);
    if (!__all(ok)) {
      float mt2[4];
#pragma unroll
      for (int r = 0; r < 4; ++r) mt2[r] = pm[r] * C2;
#pragma unroll
      for (int off = 1; off <= 8; off <<= 1)
#pragma unroll
        for (int r = 0; r < 4; ++r)
          mt2[r] = fmaxf(mt2[r], __shfl_xor(mt2[r], off));
#pragma unroll
      for (int r = 0; r < 4; ++r) {
        const float mn = fmaxf(m2[r], mt2[r]);
        const float alpha = exp2f(m2[r] - mn);   // exp2(-inf)=0 first tile
        m2[r] = mn;
        lsum[r] *= alpha;
#pragma unroll
        for (int g = 0; g < 4; ++g) oacc[g][r] *= alpha;
      }
    }

    // ---- P = exp2(s*C2 - m2); per-lane l partials; bf16 P to LDS ----
#pragma unroll
    for (int g = 0; g < 8; ++g)
#pragma unroll
      for (int r = 0; r < 4; ++r) {
        const float p = exp2f(fmaf(sacc[g][r], C2, -m2[r]));
        lsum[r] += p;
        Ps[w][lhi * 4 + r][g * 16 + lrow] = f2bf_rhu(p);
      }

    // ---- O += P V ----
    bf16x8 pa[4];
#pragma unroll
    for (int kk = 0; kk < 4; ++kk)
      pa[kk] = *(const bf16x8*)&Ps[w][lrow][kk * 32 + lhi * 8];
#pragma unroll
    for (int g = 0; g < 4; ++g)
#pragma unroll
      for (int kk = 0; kk < 4; ++kk) {
        bf16x8 vbb = *(const bf16x8*)&Vt[g * 16 + lrow][kk * 32 + lhi * 8];
        oacc[g] = __builtin_amdgcn_mfma_f32_16x16x32_bf16(pa[kk], vbb, oacc[g], 0, 0, 0);
      }
  }

  // ---- final l reduce (16-lane groups) ----
#pragma unroll
  for (int off = 1; off <= 8; off <<= 1)
#pragma unroll
    for (int r = 0; r < 4; ++r)
      lsum[r] += __shfl_xor(lsum[r], off);

  // ---- write partials ----
  const size_t pbase = ((size_t)(bh * 64 + qt) * 4 + cc) * 64;
#pragma unroll
  for (int r = 0; r < 4; ++r) {
    const int row = w * 16 + lhi * 4 + r;
    ushort* dst = P_O + (pbase + row) * 64;
#pragma unroll
    for (int g = 0; g < 4; ++g)
      dst[g * 16 + lrow] = f2bf(oacc[g][r]);
    if (lrow == 0) {
      P_m[pbase + row] = m2[r];
      P_l[pbase + row] = lsum[r];
    }
  }
}

// ---------------------------------------------------------------------------
// Combine split-KV partials -> bf16 ctx [Mm, Dd].
// One block per (qt, bh): 64 rows x 64 dims.
// ---------------------------------------------------------------------------
__global__ __launch_bounds__(256) void flash_combine(const ushort* __restrict__ P_O,
                                                     const float* __restrict__ P_m,
                                                     const float* __restrict__ P_l,
                                                     ushort* __restrict__ ctx) {
  const int qt = blockIdx.x, bh = blockIdx.y;
  const int bb = bh >> 3, hh = bh & 7;
  const int nc = (((qt + 2) >> 1) + CSTEPS - 1) / CSTEPS;
  const int t = threadIdx.x;
  const int d = t & 63, rq = t >> 6;             // 4 rows/pass, 16 passes
  const size_t pb = (size_t)(bh * 64 + qt) * 4;

  for (int rr = 0; rr < 16; ++rr) {
    const int row = rr * 4 + rq;
    float m[4], l[4];
    float mstar = -INFINITY;
#pragma unroll
    for (int c = 0; c < 4; ++c)
      if (c < nc) {
        m[c] = P_m[(pb + c) * 64 + row];
        l[c] = P_l[(pb + c) * 64 + row];
        mstar = fmaxf(mstar, m[c]);
      }
    float od = 0.f, ls = 0.f;
#pragma unroll
    for (int c = 0; c < 4; ++c)
      if (c < nc) {
        const float wc = exp2f(m[c] - mstar);
        od += wc * bf2f(P_O[((pb + c) * 64 + row) * 64 + d]);
        ls += wc * l[c];
      }
    const int sg = qt * 64 + row;
    ctx[(size_t)bb * Ss * Dd + (size_t)sg * Dd + hh * 64 + d] = f2bf(od / ls);
  }
}

// ---------------------------------------------------------------------------
// out = LayerNorm(x + a) * g + b (fp32); optionally also bf16 copy.
// ---------------------------------------------------------------------------
template<bool WB>
__global__ __launch_bounds__(128) void add_ln(const float* __restrict__ x,
                                              const float* __restrict__ a,
                                              const float* __restrict__ g,
                                              const float* __restrict__ bta,
                                              float* __restrict__ out,
                                              ushort* __restrict__ outb) {
  __shared__ float red[4];
  const int row = blockIdx.x;
  const int tid = threadIdx.x;
  const size_t off = (size_t)row * Dd + tid * 4;
  const float4 xv = *(const float4*)(x + off);
  const float4 av = *(const float4*)(a + off);
  float4 sv;
  sv.x = xv.x + av.x; sv.y = xv.y + av.y; sv.z = xv.z + av.z; sv.w = xv.w + av.w;
  float sum = sv.x + sv.y + sv.z + sv.w;
  float sq  = sv.x * sv.x + sv.y * sv.y + sv.z * sv.z + sv.w * sv.w;
#pragma unroll
  for (int o = 32; o >= 1; o >>= 1) {
    sum += __shfl_down(sum, o);
    sq  += __shfl_down(sq, o);
  }
  if ((tid & 63) == 0) { red[(tid >> 6) * 2] = sum; red[(tid >> 6) * 2 + 1] = sq; }
  __syncthreads();
  const float tot = red[0] + red[2];
  const float tsq = red[1] + red[3];
  const float invD = 1.f / 512.f;
  const float mean = tot * invD;
  const float var  = tsq * invD - mean * mean;
  const float rs   = rsqrtf(var + 1e-3f);
  const float4 gv = *(const float4*)(g + tid * 4);
  const float4 bv = *(const float4*)(bta + tid * 4);
  float4 ov;
  ov.x = (sv.x - mean) * rs * gv.x + bv.x;
  ov.y = (sv.y - mean) * rs * gv.y + bv.y;
  ov.z = (sv.z - mean) * rs * gv.z + bv.z;
  ov.w = (sv.w - mean) * rs * gv.w + bv.w;
  *(float4*)(out + off) = ov;
  if (WB) {
    ushort4 ob = {f2bf(ov.x), f2bf(ov.y), f2bf(ov.z), f2bf(ov.w)};
    *(ushort4*)(outb + off) = ob;
  }
}

// ---------------------------------------------------------------------------
// prep kernels
// ---------------------------------------------------------------------------
__global__ __launch_bounds__(256) void cast_bf16(const float* __restrict__ in,
                                                 ushort* __restrict__ out, int n4) {
  const int i = blockIdx.x * 256 + threadIdx.x;
  if (i < n4) {
    const float4 vin = ((const float4*)in)[i];
    ushort4 o = {f2bf(vin.x), f2bf(vin.y), f2bf(vin.z), f2bf(vin.w)};
    ((ushort4*)out)[i] = o;
  }
}

__global__ __launch_bounds__(256) void transpose_cast(const float* __restrict__ W,
                                                      ushort* __restrict__ Wt,
                                                      int K, int N) {
  __shared__ float tile[32][33];
  const int bk = blockIdx.y * 32, bn = blockIdx.x * 32;
  const int tx = threadIdx.x & 31, ty = threadIdx.x >> 5;
#pragma unroll
  for (int i = 0; i < 32; i += 8)
    tile[ty + i][tx] = W[(size_t)(bk + ty + i) * N + bn + tx];
  __syncthreads();
#pragma unroll
  for (int i = 0; i < 32; i += 8)
    Wt[(size_t)(bn + ty + i) * K + bk + tx] = f2bf(tile[tx][ty + i]);
}

__global__ __launch_bounds__(256) void concat3(const float* __restrict__ a,
                                               const float* __restrict__ b,
                                               const float* __restrict__ c,
                                               float* __restrict__ o) {
  const int i = blockIdx.x * 256 + threadIdx.x;  // 1536 total
  if (i < 512) o[i] = a[i];
  else if (i < 1024) o[i] = b[i - 512];
  else if (i < 1536) o[i] = c[i - 1024];
}

// ---------------------------------------------------------------------------
extern "C" void kernel_launch(void* const* d_in, const int* in_sizes, int n_in,
                              void* d_out, int out_size, void* d_ws, size_t ws_size,
                              hipStream_t stream) {
  (void)in_sizes; (void)n_in; (void)out_size; (void)ws_size;
  const float* x   = (const float*)d_in[0];
  // d_in[1] = mask: causal, applied analytically
  const float* wq  = (const float*)d_in[2];
  const float* bq  = (const float*)d_in[3];
  const float* wk  = (const float*)d_in[4];
  const float* bk  = (const float*)d_in[5];
  const float* wv  = (const float*)d_in[6];
  const float* bvp = (const float*)d_in[7];
  const float* wo  = (const float*)d_in[8];
  const float* bo  = (const float*)d_in[9];
  const float* g1  = (const float*)d_in[10];
  const float* be1 = (const float*)d_in[11];
  const float* w1  = (const float*)d_in[12];
  const float* b1  = (const float*)d_in[13];
  const float* w2  = (const float*)d_in[14];
  const float* b2  = (const float*)d_in[15];
  const float* g2  = (const float*)d_in[16];
  const float* be2 = (const float*)d_in[17];
  float* out = (float*)d_out;

  const size_t SZ  = (size_t)Mm * Dd;      // 4,194,304
  const size_t WSZ = (size_t)Dd * Dd;      // 262,144
  const size_t W1SZ = (size_t)Dd * Ff;     // 1,048,576

  float* fp = (float*)d_ws;
  float* attn_out = fp;                    // fp32 SZ
  float* y        = fp + SZ;               // fp32 SZ
  float* ffn2     = fp + 2 * SZ;           // fp32 SZ
  ushort* ub   = (ushort*)(fp + 3 * SZ);
  ushort* xb    = ub;                      // SZ
  ushort* qkvb  = ub + SZ;                 // 3*SZ  (8192 x 1536)
  ushort* ctxb  = ub + 4 * SZ;             // SZ
  ushort* yb    = ub + 5 * SZ;             // SZ
  ushort* ffn1b = ub + 6 * SZ;             // 4*SZ  (8192 x 2048); also P_O
  ushort* wqkvt = ub + 10 * SZ;            // 3*WSZ: [1536,512]
  ushort* wkt   = wqkvt + WSZ;
  ushort* wvt   = wkt + WSZ;
  ushort* wot   = wqkvt + 3 * WSZ;         // WSZ
  ushort* w1t   = wot + WSZ;               // W1SZ [2048,512]
  ushort* w2t   = w1t + W1SZ;              // W1SZ [512,2048]
  float*  bqkv  = (float*)(w2t + W1SZ);    // 1536 floats
  float*  P_m   = bqkv + 2048;             // 16*64*4*64 = 524,288 floats
  float*  P_l   = P_m + 524288;            // 524,288 floats
  ushort* P_O   = ffn1b;                   // 16.8M ushorts (dead until FFN1)

  // prep
  cast_bf16<<<dim3((int)(SZ / 4 / 256)), dim3(256), 0, stream>>>(x, xb, (int)(SZ / 4));
  transpose_cast<<<dim3(16, 16), dim3(256), 0, stream>>>(wq, wqkvt, Dd, Dd);
  transpose_cast<<<dim3(16, 16), dim3(256), 0, stream>>>(wk, wkt, Dd, Dd);
  transpose_cast<<<dim3(16, 16), dim3(256), 0, stream>>>(wv, wvt, Dd, Dd);
  transpose_cast<<<dim3(16, 16), dim3(256), 0, stream>>>(wo, wot, Dd, Dd);
  transpose_cast<<<dim3(64, 16), dim3(256), 0, stream>>>(w1, w1t, Dd, Ff);
  transpose_cast<<<dim3(16, 64), dim3(256), 0, stream>>>(w2, w2t, Ff, Dd);
  concat3<<<dim3(6), dim3(256), 0, stream>>>(bq, bk, bvp, bqkv);

  const dim3 blk(256);
  // merged QKV: [8192,512] @ [512,1536] -> [8192,1536]
  gemm_mfma<128, true,  false><<<dim3(12, 64), blk, 0, stream>>>(xb, wqkvt, bqkv, qkvb, Mm, QT3, Dd);
  // attention: split-KV partials + combine
  flash_attn_split<<<dim3(64, 64), blk, 0, stream>>>(qkvb, P_O, P_m, P_l);
  flash_combine<<<dim3(64, 16), blk, 0, stream>>>(P_O, P_m, P_l, ctxb);
  // out-proj (fp32 out for residual), BM=64 -> 512 blocks
  gemm_mfma<64,  false, false><<<dim3(4, 128), blk, 0, stream>>>(ctxb, wot, bo, attn_out, Mm, Dd, Dd);
  // LN1 (fp32 + bf16 copies)
  add_ln<true><<<dim3(8192), dim3(128), 0, stream>>>(x, attn_out, g1, be1, y, yb);
  // FFN
  gemm_mfma<128, true,  true ><<<dim3(16, 64), blk, 0, stream>>>(yb, w1t, b1, ffn1b, Mm, Ff, Dd);
  gemm_mfma<64,  false, false><<<dim3(4, 128), blk, 0, stream>>>(ffn1b, w2t, b2, ffn2, Mm, Dd, Ff);
  // LN2
  add_ln<false><<<dim3(8192), dim3(128), 0, stream>>>(y, ffn2, g2, be2, out, (ushort*)nullptr);
}